// Round 13
// baseline (187.104 us; speedup 1.0000x reference)
//
#include <hip/hip_runtime.h>

// MultiModelMLP, round 13: R12 with ONE change: mlp __launch_bounds__(256,4)
// (12 -> 16 waves/CU). Scalarized register-resident pipeline should fit the
// 128-VGPR budget (est. ~100-115 live).
// K1 bucket_img (256 blocks): two-pass queue-free bucketing, 4 two-ended
//    cursor classes per model (cls = blockIdx&3): 64-atomic chain per cursor.
// K2 mlp: fully-scalarized register-resident fp16-MFMA pipeline
//    (phi-permuted weights make D->B lane-local), 3-interval validity masks.

#define NM    64
#define HIDD  64
#define INF   6
#define OUTF  3
#define CAP   4864            // per-model region: two halves of RHALF
#define RHALF 2432            // cls0 fwd from 0, cls1 bwd to RHALF,
                              // cls2 fwd from RHALF, cls3 bwd to CAP
#define NBLKB 256

#define CSTRIDE   32
#define O_CURSORS 0           // (m*4+cls)*CSTRIDE ints
#define O_ORDER   8192        // NM*CAP sample ids
#define IWS_INTS  (O_ORDER + NM * CAP)
// then: xs fp16[NM*CAP*8] (packed L0 inputs), then weight image.

#define CONST_B   30720
#define NCONSTF   784
#define IMG_BYTES 33856

typedef _Float16 v8h __attribute__((ext_vector_type(8)));
typedef __fp16   v2hf __attribute__((ext_vector_type(2)));
typedef float    v4f __attribute__((ext_vector_type(4)));

struct BF { v8h lo, hi; };
struct PK2 { v2hf a, b; };

__device__ __host__ __forceinline__ int phi(int p) {
    int mt = p >> 4, q = (p >> 2) & 3, r = p & 3;
    return ((mt >> 1) << 5) | (q << 3) | ((mt & 1) << 2) | r;
}

// ------------------------------------------------------------ kernel 1 ----
__global__ __launch_bounds__(256, 4) void bucket_img_kernel(
    const int* __restrict__ idx, const float* __restrict__ x, int n,
    const float* __restrict__ W0, const float* __restrict__ W1,
    const float* __restrict__ W2, const float* __restrict__ W3,
    const float* __restrict__ W4,
    const float* __restrict__ B0, const float* __restrict__ G0, const float* __restrict__ H0,
    const float* __restrict__ B1, const float* __restrict__ G1, const float* __restrict__ H1,
    const float* __restrict__ B2, const float* __restrict__ G2, const float* __restrict__ H2,
    const float* __restrict__ B3, const float* __restrict__ G3, const float* __restrict__ H3,
    const float* __restrict__ B4,
    int* __restrict__ iws, _Float16* __restrict__ xs,
    unsigned char* __restrict__ imgbase) {
    __shared__ int lcnt[NM], lcur[NM];
    const int b = blockIdx.x, t = threadIdx.x;
    const int m = b >> 2, sub = b & 3;        // 4 blocks build each model image
    const int cls = b & 3;                    // cursor class

    // ---- fragment-major image, rows phi-permuted ----
    _Float16* img = (_Float16*)(imgbase + (size_t)m * IMG_BYTES);
    float* cst = (float*)(imgbase + (size_t)m * IMG_BYTES + CONST_B);
    for (int s = sub * 256 + t; s < 1920; s += 1024) {
        int f = s >> 6, l = s & 63;
        int c = l & 15, q = l >> 4;
        float vals[8];
        if (f < 4) {                          // layer 0, mt = f
            const float* wr = W0 + m * 384 + phi(f * 16 + c) * 6;
#pragma unroll
            for (int j = 0; j < 8; j++) {
                int k = q * 8 + j;
                vals[j] = (k < INF) ? wr[k] : 0.0f;
            }
        } else if (f < 28) {                  // layers 1..3
            int ll = (f - 4) >> 3, fb = (f - 4) & 7;
            int mt = fb >> 1, kh = fb & 1;
            const float* W = (ll == 0) ? W1 : (ll == 1) ? W2 : W3;
            const float* wr = W + m * 4096 + phi(mt * 16 + c) * 64 + kh * 32 + q * 8;
#pragma unroll
            for (int j = 0; j < 8; j++) vals[j] = wr[j];
        } else {                              // layer 4 (rows physical)
            int kh = f - 28;
            const float* wr = W4 + m * 192 + c * 64 + kh * 32 + q * 8;
#pragma unroll
            for (int j = 0; j < 8; j++) vals[j] = (c < OUTF) ? wr[j] : 0.0f;
        }
        v8h o;
#pragma unroll
        for (int j = 0; j < 8; j++) o[j] = (_Float16)vals[j];
        *(v8h*)(img + (size_t)s * 8) = o;
    }
    {   // consts, permuted: sub*256+t covers [0,1024) > NCONSTF
        const float* lsrc[12] = {B0, G0, H0, B1, G1, H1, B2, G2, H2, B3, G3, H3};
        int e = sub * 256 + t;
        if (e < NCONSTF) {
            float v = 0.0f;
            if (e < 768) {
                int l = e / 192, r = e - l * 192;
                v = lsrc[l * 3 + (r >> 6)][m * 64 + phi(r & 63)];
            } else if (e < 771) {
                v = B4[m * 3 + (e - 768)];
            }
            cst[e] = v;
        }
    }

    // ---- pass 1: count this block's 1024-sample segment ----
    if (t < NM) { lcnt[t] = 0; lcur[t] = 0; }
    __syncthreads();
    const int per = (n + NBLKB - 1) / NBLKB;   // 1024
    const int beg = b * per, end = min(n, beg + per);
    for (int i = beg + t; i < end; i += 256) atomicAdd(&lcnt[idx[i]], 1);
    __syncthreads();
    __shared__ int lbase[NM];
    if (t < NM)
        lbase[t] = atomicAdd(&iws[O_CURSORS + (t * 4 + cls) * CSTRIDE], lcnt[t]);
    __syncthreads();
    // ---- pass 2: scatter ids + packed fp16 x (queue-free) ----
    for (int i = beg + t; i < end; i += 256) {
        int mm = idx[i];
        int r = atomicAdd(&lcur[mm], 1);      // LDS running rank
        int rel;
        if (cls == 0)      rel = lbase[mm] + r;
        else if (cls == 1) rel = RHALF - lbase[mm] - lcnt[mm] + r;
        else if (cls == 2) rel = RHALF + lbase[mm] + r;
        else               rel = CAP - lbase[mm] - lcnt[mm] + r;
        int slot = mm * CAP + rel;
        iws[O_ORDER + slot] = i;
        const float* xp = x + (size_t)i * 6;
        float2 a0 = *(const float2*)(xp);
        float2 a1 = *(const float2*)(xp + 2);
        float2 a2 = *(const float2*)(xp + 4);
        v8h o = {};
        o[0] = (_Float16)a0.x; o[1] = (_Float16)a0.y;
        o[2] = (_Float16)a1.x; o[3] = (_Float16)a1.y;
        o[4] = (_Float16)a2.x; o[5] = (_Float16)a2.y;
        *(v8h*)(xs + (size_t)slot * 8) = o;
    }
}

// ------------------------------------------------------------ kernel 2 ----
#define MFMA16(A, B, C) __builtin_amdgcn_mfma_f32_16x16x32_f16((A), (B), (C), 0, 0, 0)

__device__ __forceinline__ PK2 epi_quad(v4f dd, const float* gp, const float* hp,
                                        float rs, float nm) {
    v4f g = *(const v4f*)gp;
    v4f h = *(const v4f*)hp;
    float y0 = fmaxf(fmaf(fmaf(dd[0], rs, nm), g[0], h[0]), 0.0f);
    float y1 = fmaxf(fmaf(fmaf(dd[1], rs, nm), g[1], h[1]), 0.0f);
    float y2 = fmaxf(fmaf(fmaf(dd[2], rs, nm), g[2], h[2]), 0.0f);
    float y3 = fmaxf(fmaf(fmaf(dd[3], rs, nm), g[3], h[3]), 0.0f);
    PK2 r;
    r.a = __builtin_amdgcn_cvt_pkrtz(y0, y1);
    r.b = __builtin_amdgcn_cvt_pkrtz(y2, y3);
    return r;
}

__device__ __forceinline__ BF layer_epilogue(v4f d0, v4f d1, v4f d2, v4f d3,
                                             const float* cb, int q) {
    float S = 0.0f, Q2 = 0.0f;
#pragma unroll
    for (int r = 0; r < 4; r++) {
        S += d0[r]; S += d1[r]; S += d2[r]; S += d3[r];
        Q2 = fmaf(d0[r], d0[r], Q2);
        Q2 = fmaf(d1[r], d1[r], Q2);
        Q2 = fmaf(d2[r], d2[r], Q2);
        Q2 = fmaf(d3[r], d3[r], Q2);
    }
    S += __shfl_xor(S, 16, 64);
    S += __shfl_xor(S, 32, 64);
    Q2 += __shfl_xor(Q2, 16, 64);
    Q2 += __shfl_xor(Q2, 32, 64);
    float mu = S * (1.0f / 64.0f);
    float var = Q2 * (1.0f / 64.0f) - mu * mu;
    float rs = rsqrtf(var + 1e-5f);
    float nm = -mu * rs;
    PK2 p0 = epi_quad(d0, cb + 64 + 0  + q * 4, cb + 128 + 0  + q * 4, rs, nm);
    PK2 p1 = epi_quad(d1, cb + 64 + 16 + q * 4, cb + 128 + 16 + q * 4, rs, nm);
    PK2 p2 = epi_quad(d2, cb + 64 + 32 + q * 4, cb + 128 + 32 + q * 4, rs, nm);
    PK2 p3 = epi_quad(d3, cb + 64 + 48 + q * 4, cb + 128 + 48 + q * 4, rs, nm);
    BF o;
    o.lo[0] = p0.a[0]; o.lo[1] = p0.a[1]; o.lo[2] = p0.b[0]; o.lo[3] = p0.b[1];
    o.lo[4] = p1.a[0]; o.lo[5] = p1.a[1]; o.lo[6] = p1.b[0]; o.lo[7] = p1.b[1];
    o.hi[0] = p2.a[0]; o.hi[1] = p2.a[1]; o.hi[2] = p2.b[0]; o.hi[3] = p2.b[1];
    o.hi[4] = p3.a[0]; o.hi[5] = p3.a[1]; o.hi[6] = p3.b[0]; o.hi[7] = p3.b[1];
    return o;
}

__device__ __forceinline__ BF l0_sample(const _Float16* xs, int slot, int q,
                                        v8h A0, v8h A1, v8h A2, v8h A3,
                                        v4f b0, v4f b1, v4f b2, v4f b3,
                                        const float* cf) {
    v8h bfr = {};
    if (q == 0) bfr = *(const v8h*)(xs + (size_t)slot * 8);
    v4f d0 = MFMA16(A0, bfr, b0);
    v4f d1 = MFMA16(A1, bfr, b1);
    v4f d2 = MFMA16(A2, bfr, b2);
    v4f d3 = MFMA16(A3, bfr, b3);
    return layer_epilogue(d0, d1, d2, d3, cf, q);
}

__device__ __forceinline__ BF mid_sample(BF h,
                                         v8h a00, v8h a01, v8h a10, v8h a11,
                                         v8h a20, v8h a21, v8h a30, v8h a31,
                                         v4f b0, v4f b1, v4f b2, v4f b3,
                                         const float* cb, int q) {
    v4f d0 = MFMA16(a00, h.lo, b0); d0 = MFMA16(a01, h.hi, d0);
    v4f d1 = MFMA16(a10, h.lo, b1); d1 = MFMA16(a11, h.hi, d1);
    v4f d2 = MFMA16(a20, h.lo, b2); d2 = MFMA16(a21, h.hi, d2);
    v4f d3 = MFMA16(a30, h.lo, b3); d3 = MFMA16(a31, h.hi, d3);
    return layer_epilogue(d0, d1, d2, d3, cb, q);
}

__device__ __forceinline__ int in_valid(int rel, int a0, int a1, int a2, int a3) {
    return (rel < a0) | ((rel >= RHALF - a1) & (rel < RHALF + a2)) |
           (rel >= CAP - a3);
}

__global__ __launch_bounds__(256, 4) void mlp_kernel(
    const int* __restrict__ iws, const _Float16* __restrict__ xs,
    const unsigned char* __restrict__ imgbase, float* __restrict__ out) {
    const int m = blockIdx.y;
    const int a0 = iws[O_CURSORS + (m * 4 + 0) * CSTRIDE];
    const int a1 = iws[O_CURSORS + (m * 4 + 1) * CSTRIDE];
    const int a2 = iws[O_CURSORS + (m * 4 + 2) * CSTRIDE];
    const int a3 = iws[O_CURSORS + (m * 4 + 3) * CSTRIDE];
    // valid rel: [0,a0) U [RHALF-a1, RHALF+a2) U [CAP-a3, CAP)
    const int C0 = blockIdx.x * 256, C1 = C0 + 256;
    if (!((C0 < a0) | ((C1 > RHALF - a1) & (C0 < RHALF + a2)) | (C1 > CAP - a3)))
        return;

    const int t = threadIdx.x, w = t >> 6, lane = t & 63;
    const int c = lane & 15, q = lane >> 4;
    const int wb = C0 + w * 64;
    if (!((wb < a0) | ((wb + 64 > RHALF - a1) & (wb < RHALF + a2)) |
          (wb + 64 > CAP - a3)))
        return;

    const _Float16* img = (const _Float16*)(imgbase + (size_t)m * IMG_BYTES);
    const float* cf = (const float*)(imgbase + (size_t)m * IMG_BYTES + CONST_B);
    const int* order = iws + O_ORDER;

    const int r0 = wb + 0 + c,  r1 = wb + 16 + c;
    const int r2 = wb + 32 + c, r3 = wb + 48 + c;
    const int v0 = in_valid(r0, a0, a1, a2, a3);
    const int v1 = in_valid(r1, a0, a1, a2, a3);
    const int v2 = in_valid(r2, a0, a1, a2, a3);
    const int v3 = in_valid(r3, a0, a1, a2, a3);
    const int s0 = m * CAP + r0, s1 = m * CAP + r1;
    const int s2 = m * CAP + r2, s3 = m * CAP + r3;
    const int sid0 = order[s0], sid1 = order[s1];
    const int sid2 = order[s2], sid3 = order[s3];

    BF h0, h1, h2, h3;

    // ---- layer 0: K=6 padded to 32; B from packed xs ----
    {
        v8h A0 = *(const v8h*)(img + 0 * 512 + lane * 8);
        v8h A1 = *(const v8h*)(img + 1 * 512 + lane * 8);
        v8h A2 = *(const v8h*)(img + 2 * 512 + lane * 8);
        v8h A3 = *(const v8h*)(img + 3 * 512 + lane * 8);
        v4f b0 = *(const v4f*)(cf + 0  + q * 4);
        v4f b1 = *(const v4f*)(cf + 16 + q * 4);
        v4f b2 = *(const v4f*)(cf + 32 + q * 4);
        v4f b3 = *(const v4f*)(cf + 48 + q * 4);
        h0 = l0_sample(xs, s0, q, A0, A1, A2, A3, b0, b1, b2, b3, cf);
        h1 = l0_sample(xs, s1, q, A0, A1, A2, A3, b0, b1, b2, b3, cf);
        h2 = l0_sample(xs, s2, q, A0, A1, A2, A3, b0, b1, b2, b3, cf);
        h3 = l0_sample(xs, s3, q, A0, A1, A2, A3, b0, b1, b2, b3, cf);
    }

    // ---- layers 1..3: register-resident chaining ----
#pragma unroll
    for (int l = 1; l <= 3; l++) {
        const _Float16* wp = img + 2048 + (l - 1) * 4096 + lane * 8;
        v8h a00 = *(const v8h*)(wp + 0 * 512);
        v8h a01 = *(const v8h*)(wp + 1 * 512);
        v8h a10 = *(const v8h*)(wp + 2 * 512);
        v8h a11 = *(const v8h*)(wp + 3 * 512);
        v8h a20 = *(const v8h*)(wp + 4 * 512);
        v8h a21 = *(const v8h*)(wp + 5 * 512);
        v8h a30 = *(const v8h*)(wp + 6 * 512);
        v8h a31 = *(const v8h*)(wp + 7 * 512);
        const float* cb = cf + l * 192;
        v4f b0 = *(const v4f*)(cb + 0  + q * 4);
        v4f b1 = *(const v4f*)(cb + 16 + q * 4);
        v4f b2 = *(const v4f*)(cb + 32 + q * 4);
        v4f b3 = *(const v4f*)(cb + 48 + q * 4);
        h0 = mid_sample(h0, a00, a01, a10, a11, a20, a21, a30, a31, b0, b1, b2, b3, cb, q);
        h1 = mid_sample(h1, a00, a01, a10, a11, a20, a21, a30, a31, b0, b1, b2, b3, cb, q);
        h2 = mid_sample(h2, a00, a01, a10, a11, a20, a21, a30, a31, b0, b1, b2, b3, cb, q);
        h3 = mid_sample(h3, a00, a01, a10, a11, a20, a21, a30, a31, b0, b1, b2, b3, cb, q);
    }

    // ---- layer 4: 64 -> 3 (rows physical, padded to 16) ----
    {
        const _Float16* wp = img + 14336 + lane * 8;
        v8h A0 = *(const v8h*)(wp);
        v8h A1 = *(const v8h*)(wp + 512);
        v4f b4i = {cf[768], cf[769], cf[770], 0.0f};
        v4f D0 = MFMA16(A0, h0.lo, b4i); D0 = MFMA16(A1, h0.hi, D0);
        v4f D1 = MFMA16(A0, h1.lo, b4i); D1 = MFMA16(A1, h1.hi, D1);
        v4f D2 = MFMA16(A0, h2.lo, b4i); D2 = MFMA16(A1, h2.hi, D2);
        v4f D3 = MFMA16(A0, h3.lo, b4i); D3 = MFMA16(A1, h3.hi, D3);
        if (q == 0) {
            if (v0) { float* op = out + (size_t)sid0 * 3; op[0] = D0[0]; op[1] = D0[1]; op[2] = D0[2]; }
            if (v1) { float* op = out + (size_t)sid1 * 3; op[0] = D1[0]; op[1] = D1[1]; op[2] = D1[2]; }
            if (v2) { float* op = out + (size_t)sid2 * 3; op[0] = D2[0]; op[1] = D2[1]; op[2] = D2[2]; }
            if (v3) { float* op = out + (size_t)sid3 * 3; op[0] = D3[0]; op[1] = D3[1]; op[2] = D3[2]; }
        }
    }
}

// -------------------------------------------------------------- launch ----
extern "C" void kernel_launch(void* const* d_in, const int* in_sizes, int n_in,
                              void* d_out, int out_size, void* d_ws, size_t ws_size,
                              hipStream_t stream) {
    const float* x  = (const float*)d_in[0];
    const int*  idx = (const int*)d_in[1];
    const float* W0 = (const float*)d_in[2];
    const float* B0 = (const float*)d_in[3];
    const float* G0 = (const float*)d_in[4];
    const float* H0 = (const float*)d_in[5];
    const float* W1 = (const float*)d_in[6];
    const float* B1 = (const float*)d_in[7];
    const float* G1 = (const float*)d_in[8];
    const float* H1 = (const float*)d_in[9];
    const float* W2 = (const float*)d_in[10];
    const float* B2 = (const float*)d_in[11];
    const float* G2 = (const float*)d_in[12];
    const float* H2 = (const float*)d_in[13];
    const float* W3 = (const float*)d_in[14];
    const float* B3 = (const float*)d_in[15];
    const float* G3 = (const float*)d_in[16];
    const float* H3 = (const float*)d_in[17];
    const float* W4 = (const float*)d_in[18];
    const float* B4 = (const float*)d_in[19];
    float* out = (float*)d_out;

    int n = in_sizes[1];
    int* iws = (int*)d_ws;
    _Float16* xs = (_Float16*)((char*)d_ws + (size_t)IWS_INTS * 4);
    unsigned char* imgbase =
        (unsigned char*)d_ws + (size_t)IWS_INTS * 4 + (size_t)NM * CAP * 16;

    (void)hipMemsetAsync(d_ws, 0, NM * 4 * CSTRIDE * sizeof(int), stream);
    bucket_img_kernel<<<dim3(NBLKB), 256, 0, stream>>>(
        idx, x, n, W0, W1, W2, W3, W4,
        B0, G0, H0, B1, G1, H1, B2, G2, H2, B3, G3, H3, B4, iws, xs, imgbase);
    // grid.x = CAP/256 = 19 chunks of 256 samples per model.
    mlp_kernel<<<dim3(19, NM), 256, 0, stream>>>(iws, xs, imgbase, out);
}

// Round 14
// 130.428 us; speedup vs baseline: 1.4345x; 1.4345x over previous
//
#include <hip/hip_runtime.h>

// MultiModelMLP, round 14: R12 with the mlp wave tile halved to 32 samples
// (2 register chains instead of 4) so live state (~110 VGPR) fits the
// 128-VGPR budget of __launch_bounds__(256,4): 16 waves/CU vs R12's 12.
// R13 proved the 4-chain pipeline needs >128 regs (spill at (256,4)).
// K1 bucket_img (256 blocks): two-pass queue-free bucketing, 4 two-ended
//    cursor classes per model (cls = blockIdx&3): 64-atomic chain per cursor.
// K2 mlp: fully-scalarized register-resident fp16-MFMA pipeline
//    (phi-permuted weights make D->B lane-local), 3-interval validity masks.

#define NM    64
#define HIDD  64
#define INF   6
#define OUTF  3
#define CAP   4864            // per-model region: two halves of RHALF
#define RHALF 2432            // cls0 fwd from 0, cls1 bwd to RHALF,
                              // cls2 fwd from RHALF, cls3 bwd to CAP
#define NBLKB 256

#define CSTRIDE   32
#define O_CURSORS 0           // (m*4+cls)*CSTRIDE ints
#define O_ORDER   8192        // NM*CAP sample ids
#define IWS_INTS  (O_ORDER + NM * CAP)
// then: xs fp16[NM*CAP*8] (packed L0 inputs), then weight image.

#define CONST_B   30720
#define NCONSTF   784
#define IMG_BYTES 33856

typedef _Float16 v8h __attribute__((ext_vector_type(8)));
typedef __fp16   v2hf __attribute__((ext_vector_type(2)));
typedef float    v4f __attribute__((ext_vector_type(4)));

struct BF { v8h lo, hi; };
struct PK2 { v2hf a, b; };

__device__ __host__ __forceinline__ int phi(int p) {
    int mt = p >> 4, q = (p >> 2) & 3, r = p & 3;
    return ((mt >> 1) << 5) | (q << 3) | ((mt & 1) << 2) | r;
}

// ------------------------------------------------------------ kernel 1 ----
__global__ __launch_bounds__(256, 4) void bucket_img_kernel(
    const int* __restrict__ idx, const float* __restrict__ x, int n,
    const float* __restrict__ W0, const float* __restrict__ W1,
    const float* __restrict__ W2, const float* __restrict__ W3,
    const float* __restrict__ W4,
    const float* __restrict__ B0, const float* __restrict__ G0, const float* __restrict__ H0,
    const float* __restrict__ B1, const float* __restrict__ G1, const float* __restrict__ H1,
    const float* __restrict__ B2, const float* __restrict__ G2, const float* __restrict__ H2,
    const float* __restrict__ B3, const float* __restrict__ G3, const float* __restrict__ H3,
    const float* __restrict__ B4,
    int* __restrict__ iws, _Float16* __restrict__ xs,
    unsigned char* __restrict__ imgbase) {
    __shared__ int lcnt[NM], lcur[NM];
    const int b = blockIdx.x, t = threadIdx.x;
    const int m = b >> 2, sub = b & 3;        // 4 blocks build each model image
    const int cls = b & 3;                    // cursor class

    // ---- fragment-major image, rows phi-permuted ----
    _Float16* img = (_Float16*)(imgbase + (size_t)m * IMG_BYTES);
    float* cst = (float*)(imgbase + (size_t)m * IMG_BYTES + CONST_B);
    for (int s = sub * 256 + t; s < 1920; s += 1024) {
        int f = s >> 6, l = s & 63;
        int c = l & 15, q = l >> 4;
        float vals[8];
        if (f < 4) {                          // layer 0, mt = f
            const float* wr = W0 + m * 384 + phi(f * 16 + c) * 6;
#pragma unroll
            for (int j = 0; j < 8; j++) {
                int k = q * 8 + j;
                vals[j] = (k < INF) ? wr[k] : 0.0f;
            }
        } else if (f < 28) {                  // layers 1..3
            int ll = (f - 4) >> 3, fb = (f - 4) & 7;
            int mt = fb >> 1, kh = fb & 1;
            const float* W = (ll == 0) ? W1 : (ll == 1) ? W2 : W3;
            const float* wr = W + m * 4096 + phi(mt * 16 + c) * 64 + kh * 32 + q * 8;
#pragma unroll
            for (int j = 0; j < 8; j++) vals[j] = wr[j];
        } else {                              // layer 4 (rows physical)
            int kh = f - 28;
            const float* wr = W4 + m * 192 + c * 64 + kh * 32 + q * 8;
#pragma unroll
            for (int j = 0; j < 8; j++) vals[j] = (c < OUTF) ? wr[j] : 0.0f;
        }
        v8h o;
#pragma unroll
        for (int j = 0; j < 8; j++) o[j] = (_Float16)vals[j];
        *(v8h*)(img + (size_t)s * 8) = o;
    }
    {   // consts, permuted: sub*256+t covers [0,1024) > NCONSTF
        const float* lsrc[12] = {B0, G0, H0, B1, G1, H1, B2, G2, H2, B3, G3, H3};
        int e = sub * 256 + t;
        if (e < NCONSTF) {
            float v = 0.0f;
            if (e < 768) {
                int l = e / 192, r = e - l * 192;
                v = lsrc[l * 3 + (r >> 6)][m * 64 + phi(r & 63)];
            } else if (e < 771) {
                v = B4[m * 3 + (e - 768)];
            }
            cst[e] = v;
        }
    }

    // ---- pass 1: count this block's 1024-sample segment ----
    if (t < NM) { lcnt[t] = 0; lcur[t] = 0; }
    __syncthreads();
    const int per = (n + NBLKB - 1) / NBLKB;   // 1024
    const int beg = b * per, end = min(n, beg + per);
    for (int i = beg + t; i < end; i += 256) atomicAdd(&lcnt[idx[i]], 1);
    __syncthreads();
    __shared__ int lbase[NM];
    if (t < NM)
        lbase[t] = atomicAdd(&iws[O_CURSORS + (t * 4 + cls) * CSTRIDE], lcnt[t]);
    __syncthreads();
    // ---- pass 2: scatter ids + packed fp16 x (queue-free) ----
    for (int i = beg + t; i < end; i += 256) {
        int mm = idx[i];
        int r = atomicAdd(&lcur[mm], 1);      // LDS running rank
        int rel;
        if (cls == 0)      rel = lbase[mm] + r;
        else if (cls == 1) rel = RHALF - lbase[mm] - lcnt[mm] + r;
        else if (cls == 2) rel = RHALF + lbase[mm] + r;
        else               rel = CAP - lbase[mm] - lcnt[mm] + r;
        int slot = mm * CAP + rel;
        iws[O_ORDER + slot] = i;
        const float* xp = x + (size_t)i * 6;
        float2 a0 = *(const float2*)(xp);
        float2 a1 = *(const float2*)(xp + 2);
        float2 a2 = *(const float2*)(xp + 4);
        v8h o = {};
        o[0] = (_Float16)a0.x; o[1] = (_Float16)a0.y;
        o[2] = (_Float16)a1.x; o[3] = (_Float16)a1.y;
        o[4] = (_Float16)a2.x; o[5] = (_Float16)a2.y;
        *(v8h*)(xs + (size_t)slot * 8) = o;
    }
}

// ------------------------------------------------------------ kernel 2 ----
#define MFMA16(A, B, C) __builtin_amdgcn_mfma_f32_16x16x32_f16((A), (B), (C), 0, 0, 0)

__device__ __forceinline__ PK2 epi_quad(v4f dd, const float* gp, const float* hp,
                                        float rs, float nm) {
    v4f g = *(const v4f*)gp;
    v4f h = *(const v4f*)hp;
    float y0 = fmaxf(fmaf(fmaf(dd[0], rs, nm), g[0], h[0]), 0.0f);
    float y1 = fmaxf(fmaf(fmaf(dd[1], rs, nm), g[1], h[1]), 0.0f);
    float y2 = fmaxf(fmaf(fmaf(dd[2], rs, nm), g[2], h[2]), 0.0f);
    float y3 = fmaxf(fmaf(fmaf(dd[3], rs, nm), g[3], h[3]), 0.0f);
    PK2 r;
    r.a = __builtin_amdgcn_cvt_pkrtz(y0, y1);
    r.b = __builtin_amdgcn_cvt_pkrtz(y2, y3);
    return r;
}

__device__ __forceinline__ BF layer_epilogue(v4f d0, v4f d1, v4f d2, v4f d3,
                                             const float* cb, int q) {
    float S = 0.0f, Q2 = 0.0f;
#pragma unroll
    for (int r = 0; r < 4; r++) {
        S += d0[r]; S += d1[r]; S += d2[r]; S += d3[r];
        Q2 = fmaf(d0[r], d0[r], Q2);
        Q2 = fmaf(d1[r], d1[r], Q2);
        Q2 = fmaf(d2[r], d2[r], Q2);
        Q2 = fmaf(d3[r], d3[r], Q2);
    }
    S += __shfl_xor(S, 16, 64);
    S += __shfl_xor(S, 32, 64);
    Q2 += __shfl_xor(Q2, 16, 64);
    Q2 += __shfl_xor(Q2, 32, 64);
    float mu = S * (1.0f / 64.0f);
    float var = Q2 * (1.0f / 64.0f) - mu * mu;
    float rs = rsqrtf(var + 1e-5f);
    float nm = -mu * rs;
    PK2 p0 = epi_quad(d0, cb + 64 + 0  + q * 4, cb + 128 + 0  + q * 4, rs, nm);
    PK2 p1 = epi_quad(d1, cb + 64 + 16 + q * 4, cb + 128 + 16 + q * 4, rs, nm);
    PK2 p2 = epi_quad(d2, cb + 64 + 32 + q * 4, cb + 128 + 32 + q * 4, rs, nm);
    PK2 p3 = epi_quad(d3, cb + 64 + 48 + q * 4, cb + 128 + 48 + q * 4, rs, nm);
    BF o;
    o.lo[0] = p0.a[0]; o.lo[1] = p0.a[1]; o.lo[2] = p0.b[0]; o.lo[3] = p0.b[1];
    o.lo[4] = p1.a[0]; o.lo[5] = p1.a[1]; o.lo[6] = p1.b[0]; o.lo[7] = p1.b[1];
    o.hi[0] = p2.a[0]; o.hi[1] = p2.a[1]; o.hi[2] = p2.b[0]; o.hi[3] = p2.b[1];
    o.hi[4] = p3.a[0]; o.hi[5] = p3.a[1]; o.hi[6] = p3.b[0]; o.hi[7] = p3.b[1];
    return o;
}

__device__ __forceinline__ BF l0_sample(const _Float16* xs, int slot, int q,
                                        v8h A0, v8h A1, v8h A2, v8h A3,
                                        v4f b0, v4f b1, v4f b2, v4f b3,
                                        const float* cf) {
    v8h bfr = {};
    if (q == 0) bfr = *(const v8h*)(xs + (size_t)slot * 8);
    v4f d0 = MFMA16(A0, bfr, b0);
    v4f d1 = MFMA16(A1, bfr, b1);
    v4f d2 = MFMA16(A2, bfr, b2);
    v4f d3 = MFMA16(A3, bfr, b3);
    return layer_epilogue(d0, d1, d2, d3, cf, q);
}

__device__ __forceinline__ BF mid_sample(BF h,
                                         v8h a00, v8h a01, v8h a10, v8h a11,
                                         v8h a20, v8h a21, v8h a30, v8h a31,
                                         v4f b0, v4f b1, v4f b2, v4f b3,
                                         const float* cb, int q) {
    v4f d0 = MFMA16(a00, h.lo, b0); d0 = MFMA16(a01, h.hi, d0);
    v4f d1 = MFMA16(a10, h.lo, b1); d1 = MFMA16(a11, h.hi, d1);
    v4f d2 = MFMA16(a20, h.lo, b2); d2 = MFMA16(a21, h.hi, d2);
    v4f d3 = MFMA16(a30, h.lo, b3); d3 = MFMA16(a31, h.hi, d3);
    return layer_epilogue(d0, d1, d2, d3, cb, q);
}

__device__ __forceinline__ int in_valid(int rel, int a0, int a1, int a2, int a3) {
    return (rel < a0) | ((rel >= RHALF - a1) & (rel < RHALF + a2)) |
           (rel >= CAP - a3);
}

__global__ __launch_bounds__(256, 4) void mlp_kernel(
    const int* __restrict__ iws, const _Float16* __restrict__ xs,
    const unsigned char* __restrict__ imgbase, float* __restrict__ out) {
    const int m = blockIdx.y;
    const int a0 = iws[O_CURSORS + (m * 4 + 0) * CSTRIDE];
    const int a1 = iws[O_CURSORS + (m * 4 + 1) * CSTRIDE];
    const int a2 = iws[O_CURSORS + (m * 4 + 2) * CSTRIDE];
    const int a3 = iws[O_CURSORS + (m * 4 + 3) * CSTRIDE];
    // valid rel: [0,a0) U [RHALF-a1, RHALF+a2) U [CAP-a3, CAP)
    const int C0 = blockIdx.x * 128, C1 = C0 + 128;
    if (!((C0 < a0) | ((C1 > RHALF - a1) & (C0 < RHALF + a2)) | (C1 > CAP - a3)))
        return;

    const int t = threadIdx.x, w = t >> 6, lane = t & 63;
    const int c = lane & 15, q = lane >> 4;
    const int wb = C0 + w * 32;
    if (!((wb < a0) | ((wb + 32 > RHALF - a1) & (wb < RHALF + a2)) |
          (wb + 32 > CAP - a3)))
        return;

    const _Float16* img = (const _Float16*)(imgbase + (size_t)m * IMG_BYTES);
    const float* cf = (const float*)(imgbase + (size_t)m * IMG_BYTES + CONST_B);
    const int* order = iws + O_ORDER;

    const int r0 = wb + 0 + c, r1 = wb + 16 + c;
    const int v0 = in_valid(r0, a0, a1, a2, a3);
    const int v1 = in_valid(r1, a0, a1, a2, a3);
    const int s0 = m * CAP + r0, s1 = m * CAP + r1;
    const int sid0 = order[s0], sid1 = order[s1];

    BF h0, h1;

    // ---- layer 0: K=6 padded to 32; B from packed xs ----
    {
        v8h A0 = *(const v8h*)(img + 0 * 512 + lane * 8);
        v8h A1 = *(const v8h*)(img + 1 * 512 + lane * 8);
        v8h A2 = *(const v8h*)(img + 2 * 512 + lane * 8);
        v8h A3 = *(const v8h*)(img + 3 * 512 + lane * 8);
        v4f b0 = *(const v4f*)(cf + 0  + q * 4);
        v4f b1 = *(const v4f*)(cf + 16 + q * 4);
        v4f b2 = *(const v4f*)(cf + 32 + q * 4);
        v4f b3 = *(const v4f*)(cf + 48 + q * 4);
        h0 = l0_sample(xs, s0, q, A0, A1, A2, A3, b0, b1, b2, b3, cf);
        h1 = l0_sample(xs, s1, q, A0, A1, A2, A3, b0, b1, b2, b3, cf);
    }

    // ---- layers 1..3: register-resident chaining ----
#pragma unroll
    for (int l = 1; l <= 3; l++) {
        const _Float16* wp = img + 2048 + (l - 1) * 4096 + lane * 8;
        v8h a00 = *(const v8h*)(wp + 0 * 512);
        v8h a01 = *(const v8h*)(wp + 1 * 512);
        v8h a10 = *(const v8h*)(wp + 2 * 512);
        v8h a11 = *(const v8h*)(wp + 3 * 512);
        v8h a20 = *(const v8h*)(wp + 4 * 512);
        v8h a21 = *(const v8h*)(wp + 5 * 512);
        v8h a30 = *(const v8h*)(wp + 6 * 512);
        v8h a31 = *(const v8h*)(wp + 7 * 512);
        const float* cb = cf + l * 192;
        v4f b0 = *(const v4f*)(cb + 0  + q * 4);
        v4f b1 = *(const v4f*)(cb + 16 + q * 4);
        v4f b2 = *(const v4f*)(cb + 32 + q * 4);
        v4f b3 = *(const v4f*)(cb + 48 + q * 4);
        h0 = mid_sample(h0, a00, a01, a10, a11, a20, a21, a30, a31, b0, b1, b2, b3, cb, q);
        h1 = mid_sample(h1, a00, a01, a10, a11, a20, a21, a30, a31, b0, b1, b2, b3, cb, q);
    }

    // ---- layer 4: 64 -> 3 (rows physical, padded to 16) ----
    {
        const _Float16* wp = img + 14336 + lane * 8;
        v8h A0 = *(const v8h*)(wp);
        v8h A1 = *(const v8h*)(wp + 512);
        v4f b4i = {cf[768], cf[769], cf[770], 0.0f};
        v4f D0 = MFMA16(A0, h0.lo, b4i); D0 = MFMA16(A1, h0.hi, D0);
        v4f D1 = MFMA16(A0, h1.lo, b4i); D1 = MFMA16(A1, h1.hi, D1);
        if (q == 0) {
            if (v0) { float* op = out + (size_t)sid0 * 3; op[0] = D0[0]; op[1] = D0[1]; op[2] = D0[2]; }
            if (v1) { float* op = out + (size_t)sid1 * 3; op[0] = D1[0]; op[1] = D1[1]; op[2] = D1[2]; }
        }
    }
}

// -------------------------------------------------------------- launch ----
extern "C" void kernel_launch(void* const* d_in, const int* in_sizes, int n_in,
                              void* d_out, int out_size, void* d_ws, size_t ws_size,
                              hipStream_t stream) {
    const float* x  = (const float*)d_in[0];
    const int*  idx = (const int*)d_in[1];
    const float* W0 = (const float*)d_in[2];
    const float* B0 = (const float*)d_in[3];
    const float* G0 = (const float*)d_in[4];
    const float* H0 = (const float*)d_in[5];
    const float* W1 = (const float*)d_in[6];
    const float* B1 = (const float*)d_in[7];
    const float* G1 = (const float*)d_in[8];
    const float* H1 = (const float*)d_in[9];
    const float* W2 = (const float*)d_in[10];
    const float* B2 = (const float*)d_in[11];
    const float* G2 = (const float*)d_in[12];
    const float* H2 = (const float*)d_in[13];
    const float* W3 = (const float*)d_in[14];
    const float* B3 = (const float*)d_in[15];
    const float* G3 = (const float*)d_in[16];
    const float* H3 = (const float*)d_in[17];
    const float* W4 = (const float*)d_in[18];
    const float* B4 = (const float*)d_in[19];
    float* out = (float*)d_out;

    int n = in_sizes[1];
    int* iws = (int*)d_ws;
    _Float16* xs = (_Float16*)((char*)d_ws + (size_t)IWS_INTS * 4);
    unsigned char* imgbase =
        (unsigned char*)d_ws + (size_t)IWS_INTS * 4 + (size_t)NM * CAP * 16;

    (void)hipMemsetAsync(d_ws, 0, NM * 4 * CSTRIDE * sizeof(int), stream);
    bucket_img_kernel<<<dim3(NBLKB), 256, 0, stream>>>(
        idx, x, n, W0, W1, W2, W3, W4,
        B0, G0, H0, B1, G1, H1, B2, G2, H2, B3, G3, H3, B4, iws, xs, imgbase);
    // grid.x = CAP/128 = 38 chunks of 128 samples per model.
    mlp_kernel<<<dim3(38, NM), 256, 0, stream>>>(iws, xs, imgbase, out);
}

// Round 15
// 125.917 us; speedup vs baseline: 1.4859x; 1.0358x over previous
//
#include <hip/hip_runtime.h>

// MultiModelMLP, round 15: R12 (champion, 127.8) with ONE change: the packed
// xs array is gone — bucket writes only order[]; mlp's L0 gathers x[sid]
// directly (fp32->fp16 inline, 16 lanes/wave, latency hidden), with
// validity-masked sid to avoid OOB on poisoned hole slots.
// K1 bucket_img (256 blocks): two-pass queue-free bucketing, 4 two-ended
//    cursor classes per model (cls = blockIdx&3): 64-atomic chain per cursor.
// K2 mlp (256,3): fully-scalarized register-resident fp16-MFMA pipeline
//    (phi-permuted weights make D->B lane-local), 3-interval validity masks.

#define NM    64
#define HIDD  64
#define INF   6
#define OUTF  3
#define CAP   4864            // per-model region: two halves of RHALF
#define RHALF 2432            // cls0 fwd from 0, cls1 bwd to RHALF,
                              // cls2 fwd from RHALF, cls3 bwd to CAP
#define NBLKB 256

#define CSTRIDE   32
#define O_CURSORS 0           // (m*4+cls)*CSTRIDE ints
#define O_ORDER   8192        // NM*CAP sample ids
#define IWS_INTS  (O_ORDER + NM * CAP)
// then: weight image.

#define CONST_B   30720
#define NCONSTF   784
#define IMG_BYTES 33856

typedef _Float16 v8h __attribute__((ext_vector_type(8)));
typedef __fp16   v2hf __attribute__((ext_vector_type(2)));
typedef float    v4f __attribute__((ext_vector_type(4)));

struct BF { v8h lo, hi; };
struct PK2 { v2hf a, b; };

__device__ __host__ __forceinline__ int phi(int p) {
    int mt = p >> 4, q = (p >> 2) & 3, r = p & 3;
    return ((mt >> 1) << 5) | (q << 3) | ((mt & 1) << 2) | r;
}

// ------------------------------------------------------------ kernel 1 ----
__global__ __launch_bounds__(256, 4) void bucket_img_kernel(
    const int* __restrict__ idx, int n,
    const float* __restrict__ W0, const float* __restrict__ W1,
    const float* __restrict__ W2, const float* __restrict__ W3,
    const float* __restrict__ W4,
    const float* __restrict__ B0, const float* __restrict__ G0, const float* __restrict__ H0,
    const float* __restrict__ B1, const float* __restrict__ G1, const float* __restrict__ H1,
    const float* __restrict__ B2, const float* __restrict__ G2, const float* __restrict__ H2,
    const float* __restrict__ B3, const float* __restrict__ G3, const float* __restrict__ H3,
    const float* __restrict__ B4,
    int* __restrict__ iws, unsigned char* __restrict__ imgbase) {
    __shared__ int lcnt[NM], lcur[NM];
    const int b = blockIdx.x, t = threadIdx.x;
    const int m = b >> 2, sub = b & 3;        // 4 blocks build each model image
    const int cls = b & 3;                    // cursor class

    // ---- fragment-major image, rows phi-permuted ----
    _Float16* img = (_Float16*)(imgbase + (size_t)m * IMG_BYTES);
    float* cst = (float*)(imgbase + (size_t)m * IMG_BYTES + CONST_B);
    for (int s = sub * 256 + t; s < 1920; s += 1024) {
        int f = s >> 6, l = s & 63;
        int c = l & 15, q = l >> 4;
        float vals[8];
        if (f < 4) {                          // layer 0, mt = f
            const float* wr = W0 + m * 384 + phi(f * 16 + c) * 6;
#pragma unroll
            for (int j = 0; j < 8; j++) {
                int k = q * 8 + j;
                vals[j] = (k < INF) ? wr[k] : 0.0f;
            }
        } else if (f < 28) {                  // layers 1..3
            int ll = (f - 4) >> 3, fb = (f - 4) & 7;
            int mt = fb >> 1, kh = fb & 1;
            const float* W = (ll == 0) ? W1 : (ll == 1) ? W2 : W3;
            const float* wr = W + m * 4096 + phi(mt * 16 + c) * 64 + kh * 32 + q * 8;
#pragma unroll
            for (int j = 0; j < 8; j++) vals[j] = wr[j];
        } else {                              // layer 4 (rows physical)
            int kh = f - 28;
            const float* wr = W4 + m * 192 + c * 64 + kh * 32 + q * 8;
#pragma unroll
            for (int j = 0; j < 8; j++) vals[j] = (c < OUTF) ? wr[j] : 0.0f;
        }
        v8h o;
#pragma unroll
        for (int j = 0; j < 8; j++) o[j] = (_Float16)vals[j];
        *(v8h*)(img + (size_t)s * 8) = o;
    }
    {   // consts, permuted: sub*256+t covers [0,1024) > NCONSTF
        const float* lsrc[12] = {B0, G0, H0, B1, G1, H1, B2, G2, H2, B3, G3, H3};
        int e = sub * 256 + t;
        if (e < NCONSTF) {
            float v = 0.0f;
            if (e < 768) {
                int l = e / 192, r = e - l * 192;
                v = lsrc[l * 3 + (r >> 6)][m * 64 + phi(r & 63)];
            } else if (e < 771) {
                v = B4[m * 3 + (e - 768)];
            }
            cst[e] = v;
        }
    }

    // ---- pass 1: count this block's 1024-sample segment ----
    if (t < NM) { lcnt[t] = 0; lcur[t] = 0; }
    __syncthreads();
    const int per = (n + NBLKB - 1) / NBLKB;   // 1024
    const int beg = b * per, end = min(n, beg + per);
    for (int i = beg + t; i < end; i += 256) atomicAdd(&lcnt[idx[i]], 1);
    __syncthreads();
    __shared__ int lbase[NM];
    if (t < NM)
        lbase[t] = atomicAdd(&iws[O_CURSORS + (t * 4 + cls) * CSTRIDE], lcnt[t]);
    __syncthreads();
    // ---- pass 2: scatter sample ids only (no xs pack) ----
    for (int i = beg + t; i < end; i += 256) {
        int mm = idx[i];
        int r = atomicAdd(&lcur[mm], 1);      // LDS running rank
        int rel;
        if (cls == 0)      rel = lbase[mm] + r;
        else if (cls == 1) rel = RHALF - lbase[mm] - lcnt[mm] + r;
        else if (cls == 2) rel = RHALF + lbase[mm] + r;
        else               rel = CAP - lbase[mm] - lcnt[mm] + r;
        iws[O_ORDER + mm * CAP + rel] = i;
    }
}

// ------------------------------------------------------------ kernel 2 ----
#define MFMA16(A, B, C) __builtin_amdgcn_mfma_f32_16x16x32_f16((A), (B), (C), 0, 0, 0)

__device__ __forceinline__ PK2 epi_quad(v4f dd, const float* gp, const float* hp,
                                        float rs, float nm) {
    v4f g = *(const v4f*)gp;
    v4f h = *(const v4f*)hp;
    float y0 = fmaxf(fmaf(fmaf(dd[0], rs, nm), g[0], h[0]), 0.0f);
    float y1 = fmaxf(fmaf(fmaf(dd[1], rs, nm), g[1], h[1]), 0.0f);
    float y2 = fmaxf(fmaf(fmaf(dd[2], rs, nm), g[2], h[2]), 0.0f);
    float y3 = fmaxf(fmaf(fmaf(dd[3], rs, nm), g[3], h[3]), 0.0f);
    PK2 r;
    r.a = __builtin_amdgcn_cvt_pkrtz(y0, y1);
    r.b = __builtin_amdgcn_cvt_pkrtz(y2, y3);
    return r;
}

__device__ __forceinline__ BF layer_epilogue(v4f d0, v4f d1, v4f d2, v4f d3,
                                             const float* cb, int q) {
    float S = 0.0f, Q2 = 0.0f;
#pragma unroll
    for (int r = 0; r < 4; r++) {
        S += d0[r]; S += d1[r]; S += d2[r]; S += d3[r];
        Q2 = fmaf(d0[r], d0[r], Q2);
        Q2 = fmaf(d1[r], d1[r], Q2);
        Q2 = fmaf(d2[r], d2[r], Q2);
        Q2 = fmaf(d3[r], d3[r], Q2);
    }
    S += __shfl_xor(S, 16, 64);
    S += __shfl_xor(S, 32, 64);
    Q2 += __shfl_xor(Q2, 16, 64);
    Q2 += __shfl_xor(Q2, 32, 64);
    float mu = S * (1.0f / 64.0f);
    float var = Q2 * (1.0f / 64.0f) - mu * mu;
    float rs = rsqrtf(var + 1e-5f);
    float nm = -mu * rs;
    PK2 p0 = epi_quad(d0, cb + 64 + 0  + q * 4, cb + 128 + 0  + q * 4, rs, nm);
    PK2 p1 = epi_quad(d1, cb + 64 + 16 + q * 4, cb + 128 + 16 + q * 4, rs, nm);
    PK2 p2 = epi_quad(d2, cb + 64 + 32 + q * 4, cb + 128 + 32 + q * 4, rs, nm);
    PK2 p3 = epi_quad(d3, cb + 64 + 48 + q * 4, cb + 128 + 48 + q * 4, rs, nm);
    BF o;
    o.lo[0] = p0.a[0]; o.lo[1] = p0.a[1]; o.lo[2] = p0.b[0]; o.lo[3] = p0.b[1];
    o.lo[4] = p1.a[0]; o.lo[5] = p1.a[1]; o.lo[6] = p1.b[0]; o.lo[7] = p1.b[1];
    o.hi[0] = p2.a[0]; o.hi[1] = p2.a[1]; o.hi[2] = p2.b[0]; o.hi[3] = p2.b[1];
    o.hi[4] = p3.a[0]; o.hi[5] = p3.a[1]; o.hi[6] = p3.b[0]; o.hi[7] = p3.b[1];
    return o;
}

__device__ __forceinline__ BF l0_sample(const float* __restrict__ x, int sid, int q,
                                        v8h A0, v8h A1, v8h A2, v8h A3,
                                        v4f b0, v4f b1, v4f b2, v4f b3,
                                        const float* cf) {
    v8h bfr = {};
    if (q == 0) {                    // direct gather; sid pre-masked to valid
        const float* xp = x + (size_t)sid * 6;
        float2 a0 = *(const float2*)(xp);
        float2 a1 = *(const float2*)(xp + 2);
        float2 a2 = *(const float2*)(xp + 4);
        bfr[0] = (_Float16)a0.x; bfr[1] = (_Float16)a0.y;
        bfr[2] = (_Float16)a1.x; bfr[3] = (_Float16)a1.y;
        bfr[4] = (_Float16)a2.x; bfr[5] = (_Float16)a2.y;
    }
    v4f d0 = MFMA16(A0, bfr, b0);
    v4f d1 = MFMA16(A1, bfr, b1);
    v4f d2 = MFMA16(A2, bfr, b2);
    v4f d3 = MFMA16(A3, bfr, b3);
    return layer_epilogue(d0, d1, d2, d3, cf, q);
}

__device__ __forceinline__ BF mid_sample(BF h,
                                         v8h a00, v8h a01, v8h a10, v8h a11,
                                         v8h a20, v8h a21, v8h a30, v8h a31,
                                         v4f b0, v4f b1, v4f b2, v4f b3,
                                         const float* cb, int q) {
    v4f d0 = MFMA16(a00, h.lo, b0); d0 = MFMA16(a01, h.hi, d0);
    v4f d1 = MFMA16(a10, h.lo, b1); d1 = MFMA16(a11, h.hi, d1);
    v4f d2 = MFMA16(a20, h.lo, b2); d2 = MFMA16(a21, h.hi, d2);
    v4f d3 = MFMA16(a30, h.lo, b3); d3 = MFMA16(a31, h.hi, d3);
    return layer_epilogue(d0, d1, d2, d3, cb, q);
}

__device__ __forceinline__ int in_valid(int rel, int a0, int a1, int a2, int a3) {
    return (rel < a0) | ((rel >= RHALF - a1) & (rel < RHALF + a2)) |
           (rel >= CAP - a3);
}

__global__ __launch_bounds__(256, 3) void mlp_kernel(
    const int* __restrict__ iws, const float* __restrict__ x,
    const unsigned char* __restrict__ imgbase, float* __restrict__ out) {
    const int m = blockIdx.y;
    const int a0 = iws[O_CURSORS + (m * 4 + 0) * CSTRIDE];
    const int a1 = iws[O_CURSORS + (m * 4 + 1) * CSTRIDE];
    const int a2 = iws[O_CURSORS + (m * 4 + 2) * CSTRIDE];
    const int a3 = iws[O_CURSORS + (m * 4 + 3) * CSTRIDE];
    // valid rel: [0,a0) U [RHALF-a1, RHALF+a2) U [CAP-a3, CAP)
    const int C0 = blockIdx.x * 256, C1 = C0 + 256;
    if (!((C0 < a0) | ((C1 > RHALF - a1) & (C0 < RHALF + a2)) | (C1 > CAP - a3)))
        return;

    const int t = threadIdx.x, w = t >> 6, lane = t & 63;
    const int c = lane & 15, q = lane >> 4;
    const int wb = C0 + w * 64;
    if (!((wb < a0) | ((wb + 64 > RHALF - a1) & (wb < RHALF + a2)) |
          (wb + 64 > CAP - a3)))
        return;

    const _Float16* img = (const _Float16*)(imgbase + (size_t)m * IMG_BYTES);
    const float* cf = (const float*)(imgbase + (size_t)m * IMG_BYTES + CONST_B);
    const int* order = iws + O_ORDER;

    const int r0 = wb + 0 + c,  r1 = wb + 16 + c;
    const int r2 = wb + 32 + c, r3 = wb + 48 + c;
    const int v0 = in_valid(r0, a0, a1, a2, a3);
    const int v1 = in_valid(r1, a0, a1, a2, a3);
    const int v2 = in_valid(r2, a0, a1, a2, a3);
    const int v3 = in_valid(r3, a0, a1, a2, a3);
    // masked sid: hole slots hold poison -> clamp to 0 (in-bounds, unused)
    const int sid0 = v0 ? order[m * CAP + r0] : 0;
    const int sid1 = v1 ? order[m * CAP + r1] : 0;
    const int sid2 = v2 ? order[m * CAP + r2] : 0;
    const int sid3 = v3 ? order[m * CAP + r3] : 0;

    BF h0, h1, h2, h3;

    // ---- layer 0: K=6 padded to 32; B gathered from x ----
    {
        v8h A0 = *(const v8h*)(img + 0 * 512 + lane * 8);
        v8h A1 = *(const v8h*)(img + 1 * 512 + lane * 8);
        v8h A2 = *(const v8h*)(img + 2 * 512 + lane * 8);
        v8h A3 = *(const v8h*)(img + 3 * 512 + lane * 8);
        v4f b0 = *(const v4f*)(cf + 0  + q * 4);
        v4f b1 = *(const v4f*)(cf + 16 + q * 4);
        v4f b2 = *(const v4f*)(cf + 32 + q * 4);
        v4f b3 = *(const v4f*)(cf + 48 + q * 4);
        h0 = l0_sample(x, sid0, q, A0, A1, A2, A3, b0, b1, b2, b3, cf);
        h1 = l0_sample(x, sid1, q, A0, A1, A2, A3, b0, b1, b2, b3, cf);
        h2 = l0_sample(x, sid2, q, A0, A1, A2, A3, b0, b1, b2, b3, cf);
        h3 = l0_sample(x, sid3, q, A0, A1, A2, A3, b0, b1, b2, b3, cf);
    }

    // ---- layers 1..3: register-resident chaining ----
#pragma unroll
    for (int l = 1; l <= 3; l++) {
        const _Float16* wp = img + 2048 + (l - 1) * 4096 + lane * 8;
        v8h a00 = *(const v8h*)(wp + 0 * 512);
        v8h a01 = *(const v8h*)(wp + 1 * 512);
        v8h a10 = *(const v8h*)(wp + 2 * 512);
        v8h a11 = *(const v8h*)(wp + 3 * 512);
        v8h a20 = *(const v8h*)(wp + 4 * 512);
        v8h a21 = *(const v8h*)(wp + 5 * 512);
        v8h a30 = *(const v8h*)(wp + 6 * 512);
        v8h a31 = *(const v8h*)(wp + 7 * 512);
        const float* cb = cf + l * 192;
        v4f b0 = *(const v4f*)(cb + 0  + q * 4);
        v4f b1 = *(const v4f*)(cb + 16 + q * 4);
        v4f b2 = *(const v4f*)(cb + 32 + q * 4);
        v4f b3 = *(const v4f*)(cb + 48 + q * 4);
        h0 = mid_sample(h0, a00, a01, a10, a11, a20, a21, a30, a31, b0, b1, b2, b3, cb, q);
        h1 = mid_sample(h1, a00, a01, a10, a11, a20, a21, a30, a31, b0, b1, b2, b3, cb, q);
        h2 = mid_sample(h2, a00, a01, a10, a11, a20, a21, a30, a31, b0, b1, b2, b3, cb, q);
        h3 = mid_sample(h3, a00, a01, a10, a11, a20, a21, a30, a31, b0, b1, b2, b3, cb, q);
    }

    // ---- layer 4: 64 -> 3 (rows physical, padded to 16) ----
    {
        const _Float16* wp = img + 14336 + lane * 8;
        v8h A0 = *(const v8h*)(wp);
        v8h A1 = *(const v8h*)(wp + 512);
        v4f b4i = {cf[768], cf[769], cf[770], 0.0f};
        v4f D0 = MFMA16(A0, h0.lo, b4i); D0 = MFMA16(A1, h0.hi, D0);
        v4f D1 = MFMA16(A0, h1.lo, b4i); D1 = MFMA16(A1, h1.hi, D1);
        v4f D2 = MFMA16(A0, h2.lo, b4i); D2 = MFMA16(A1, h2.hi, D2);
        v4f D3 = MFMA16(A0, h3.lo, b4i); D3 = MFMA16(A1, h3.hi, D3);
        if (q == 0) {
            if (v0) { float* op = out + (size_t)sid0 * 3; op[0] = D0[0]; op[1] = D0[1]; op[2] = D0[2]; }
            if (v1) { float* op = out + (size_t)sid1 * 3; op[0] = D1[0]; op[1] = D1[1]; op[2] = D1[2]; }
            if (v2) { float* op = out + (size_t)sid2 * 3; op[0] = D2[0]; op[1] = D2[1]; op[2] = D2[2]; }
            if (v3) { float* op = out + (size_t)sid3 * 3; op[0] = D3[0]; op[1] = D3[1]; op[2] = D3[2]; }
        }
    }
}

// -------------------------------------------------------------- launch ----
extern "C" void kernel_launch(void* const* d_in, const int* in_sizes, int n_in,
                              void* d_out, int out_size, void* d_ws, size_t ws_size,
                              hipStream_t stream) {
    const float* x  = (const float*)d_in[0];
    const int*  idx = (const int*)d_in[1];
    const float* W0 = (const float*)d_in[2];
    const float* B0 = (const float*)d_in[3];
    const float* G0 = (const float*)d_in[4];
    const float* H0 = (const float*)d_in[5];
    const float* W1 = (const float*)d_in[6];
    const float* B1 = (const float*)d_in[7];
    const float* G1 = (const float*)d_in[8];
    const float* H1 = (const float*)d_in[9];
    const float* W2 = (const float*)d_in[10];
    const float* B2 = (const float*)d_in[11];
    const float* G2 = (const float*)d_in[12];
    const float* H2 = (const float*)d_in[13];
    const float* W3 = (const float*)d_in[14];
    const float* B3 = (const float*)d_in[15];
    const float* G3 = (const float*)d_in[16];
    const float* H3 = (const float*)d_in[17];
    const float* W4 = (const float*)d_in[18];
    const float* B4 = (const float*)d_in[19];
    float* out = (float*)d_out;

    int n = in_sizes[1];
    int* iws = (int*)d_ws;
    unsigned char* imgbase = (unsigned char*)d_ws + (size_t)IWS_INTS * 4;

    (void)hipMemsetAsync(d_ws, 0, NM * 4 * CSTRIDE * sizeof(int), stream);
    bucket_img_kernel<<<dim3(NBLKB), 256, 0, stream>>>(
        idx, n, W0, W1, W2, W3, W4,
        B0, G0, H0, B1, G1, H1, B2, G2, H2, B3, G3, H3, B4, iws, imgbase);
    // grid.x = CAP/256 = 19 chunks of 256 samples per model.
    mlp_kernel<<<dim3(19, NM), 256, 0, stream>>>(iws, x, imgbase, out);
}